// Round 6
// baseline (311.234 us; speedup 1.0000x reference)
//
#include <hip/hip_runtime.h>
#include <type_traits>

// Problem constants (ExaoneFlashAttention): B=4, S=1024, T=4096, D_MODEL=2048,
// H=32, KVH=8, HD=64, GROUPS=4, SCALE=1/8. All bf16 MFMA, f32 accum.
// Attention scale * log2(e) folded into Wq transpose -> softmax in exp2 domain.
// Max-free softmax (logits bounded); RoPE fused into the QKV GEMM epilogue.
// GEMM staging: BK=32 paired-row LDS layout (two 64B k-rows per 128B line,
// XOR-swizzled) -> conflict-free b128 fragment reads at the fine-grained
// 4-DMA drain granularity that measured fastest (R5 post-mortem).

typedef __bf16 bf16x8 __attribute__((ext_vector_type(8)));
typedef __bf16 bf16x4 __attribute__((ext_vector_type(4)));
typedef float f32x4 __attribute__((ext_vector_type(4)));
typedef unsigned short u16;
typedef unsigned int u32;

#define DEVI __device__ __forceinline__

DEVI u16 f2bf(float f) {           // RNE f32->bf16 (finite inputs)
  u32 u = __builtin_bit_cast(u32, f);
  u += 0x7FFF + ((u >> 16) & 1);
  return (u16)(u >> 16);
}

// async global->LDS, 16B per lane. LDS dest must be wave-uniform base + lane*16.
DEVI void ld16_lds(const void* g, void* l) {
  __builtin_amdgcn_global_load_lds((const __attribute__((address_space(1))) u32*)g,
                                   (__attribute__((address_space(3))) u32*)l, 16, 0, 0);
}

// ---------------- merged prep: hs f32->bf16 convert + 4 weight transposes ----------------
// blockIdx.x ranges: [0,8192) convert; then Wq 64x64, Wk 16x64, Wv 16x64, Wo 64x64.
__global__ __launch_bounds__(256) void prep(const float* __restrict__ hs, u16* __restrict__ hsB,
                                            const float* __restrict__ Wq, const float* __restrict__ Wk,
                                            const float* __restrict__ Wv, const float* __restrict__ Wo,
                                            u16* __restrict__ wqkvT, u16* __restrict__ woT,
                                            float qscale) {
  int bx = blockIdx.x;
  if (bx < 8192) {                     // convert: 8192*256*4 = 4096*2048 elements
    int i = bx * 256 + threadIdx.x;
    float4 v = ((const float4*)hs)[i];
    ushort4 o;
    o.x = f2bf(v.x); o.y = f2bf(v.y); o.z = f2bf(v.z); o.w = f2bf(v.w);
    ((ushort4*)hsB)[i] = o;
    return;
  }
  bx -= 8192;
  const float* src; u16* dst; int C; float scale; int bxx, bxy;
  if (bx < 4096)      { src = Wq; dst = wqkvT;                      C = 2048; scale = qscale;
                        bxx = bx & 63; bxy = bx >> 6; }
  else if (bx < 5120) { bx -= 4096; src = Wk; dst = wqkvT + (size_t)2048 * 2048; C = 512; scale = 1.f;
                        bxx = bx & 15; bxy = bx >> 4; }
  else if (bx < 6144) { bx -= 5120; src = Wv; dst = wqkvT + (size_t)2560 * 2048; C = 512; scale = 1.f;
                        bxx = bx & 15; bxy = bx >> 4; }
  else                { bx -= 6144; src = Wo; dst = woT;            C = 2048; scale = 1.f;
                        bxx = bx & 63; bxy = bx >> 6; }
  const int R = 2048;
  __shared__ float tile[32][33];
  int c0 = bxx * 32, r0 = bxy * 32;
  int tx = threadIdx.x & 31, ty = threadIdx.x >> 5;   // ty 0..7
#pragma unroll
  for (int i = 0; i < 32; i += 8)
    tile[ty + i][tx] = src[(size_t)(r0 + ty + i) * C + (c0 + tx)];
  __syncthreads();
#pragma unroll
  for (int i = 0; i < 32; i += 8)
    dst[(size_t)(c0 + ty + i) * R + (r0 + tx)] = f2bf(tile[tx][ty + i] * scale);
}

// ---------------- GEMM: C(MxN) = A(MxK) * BT(NxK)^T, bf16 in, f32 acc ----------------
// 128x128 tile, 256 thr (4 waves, each 64x64 = 4x4 MFMA tiles), BK=32.
// Paired-row LDS: row r lives in super-row r>>1 at chunk ((r&1)*4 + c) ^ ((r>>1)&7).
// 8-lane b128 phases hit 8 distinct chunk positions -> conflict-free.
// ROPE: rotary applied in-register before the bf16 pack (QKV gemm, cols < 2560;
// pair (d, d+32) = (acc[i][j], acc[i][j+2]) of the same lane).
template <typename OutT, bool ROPE>
__global__ __launch_bounds__(256) void gemm_bt(const u16* __restrict__ A, const u16* __restrict__ BT,
                                               OutT* __restrict__ C, int M, int N, int K,
                                               const float* __restrict__ cs,
                                               const float* __restrict__ sn) {
  __shared__ u16 As[64 * 64];   // 64 super-rows x 128B = 8KB  (128 rows x 32 k)
  __shared__ u16 Bs[64 * 64];
  const int tid = threadIdx.x;
  const int lane = tid & 63, wave = tid >> 6;
  const int quad = lane >> 4, l16 = lane & 15;
  const int m0 = blockIdx.y * 128, n0 = blockIdx.x * 128;
  const int wr = (wave >> 1) * 64, wc = (wave & 1) * 64;

  f32x4 acc[4][4] = {};

  // staging source mapping: dest u16 = tid*8 (+j*2048) -> (super, pos) -> (row, chunk)
  const int s_local = tid >> 3;              // 0..31
  const int pos = tid & 7;
  const int v = pos ^ (s_local & 7);
  const int base_r = 2 * s_local + (v >> 2); // 0..63 (region j adds 64j)
  const int c0 = v & 3;                      // source 16B chunk within the 64B k-row
  const u16* Ag = A + (size_t)(m0 + base_r) * K + c0 * 8;
  const u16* Bg = BT + (size_t)(n0 + base_r) * K + c0 * 8;

  for (int k0 = 0; k0 < K; k0 += 32) {
    __syncthreads();
    ld16_lds(Ag + k0, &As[tid * 8]);
    ld16_lds(Ag + k0 + (size_t)64 * K, &As[tid * 8 + 2048]);
    ld16_lds(Bg + k0, &Bs[tid * 8]);
    ld16_lds(Bg + k0 + (size_t)64 * K, &Bs[tid * 8 + 2048]);
    __syncthreads();   // vmcnt drain before use

    bf16x8 af[4], bfr[4];
#pragma unroll
    for (int i = 0; i < 4; i++) {
      int ar = wr + i * 16 + l16;
      af[i] = *(const bf16x8*)&As[(ar >> 1) * 64 + ((((ar & 1) * 4 + quad) ^ ((ar >> 1) & 7)) * 8)];
      int br = wc + i * 16 + l16;
      bfr[i] = *(const bf16x8*)&Bs[(br >> 1) * 64 + ((((br & 1) * 4 + quad) ^ ((br >> 1) & 7)) * 8)];
    }
#pragma unroll
    for (int i = 0; i < 4; i++)
#pragma unroll
      for (int j = 0; j < 4; j++)
        acc[i][j] = __builtin_amdgcn_mfma_f32_16x16x32_bf16(af[i], bfr[j], acc[i][j], 0, 0, 0);
  }

  // ---- fused RoPE (QKV gemm, Q/K columns only; wave-uniform branch) ----
  if constexpr (ROPE) {
    if (n0 + wc < 2560) {
#pragma unroll
      for (int i = 0; i < 4; i++) {
        int t0 = m0 + wr + i * 16 + quad * 4;
#pragma unroll
        for (int jj = 0; jj < 2; jj++) {
          int d = jj * 16 + l16;            // head-dim 0..31
#pragma unroll
          for (int r = 0; r < 4; r++) {
            float c = cs[(size_t)(t0 + r) * 32 + d];
            float s = sn[(size_t)(t0 + r) * 32 + d];
            float x1 = acc[i][jj][r], x2 = acc[i][jj + 2][r];
            acc[i][jj][r] = x1 * c - x2 * s;
            acc[i][jj + 2][r] = x2 * c + x1 * s;
          }
        }
      }
    }
  }

  // epilogue: C/D layout col=lane&15, row=quad*4+r
#pragma unroll
  for (int i = 0; i < 4; i++) {
    int row = m0 + wr + i * 16 + quad * 4;
#pragma unroll
    for (int j = 0; j < 4; j++) {
      int col = n0 + wc + j * 16 + l16;
#pragma unroll
      for (int r = 0; r < 4; r++) {
        size_t off = (size_t)(row + r) * N + col;
        if constexpr (sizeof(OutT) == 2) C[off] = f2bf(acc[i][j][r]);
        else C[off] = acc[i][j][r];
      }
    }
  }
}

// ---------------- vkt_build: V -> transposed, chunk-swizzled, k-permuted tile images ----
__global__ __launch_bounds__(256) void vkt_build(const u16* __restrict__ qkv,
                                                 u16* __restrict__ vkt) {
  __shared__ u16 Vn[128 * 64];
  const int kt = blockIdx.x, kvh = blockIdx.y, b = blockIdx.z;
  const int tid = threadIdx.x;
  const u16* src = qkv + ((size_t)b * 1024 + kt * 128) * 3072 + 2560 + kvh * 64;
  {
    int tok = tid >> 1, hf = tid & 1;
    const uint4* s4 = (const uint4*)(src + (size_t)tok * 3072 + hf * 32);
    uint4* d4 = (uint4*)&Vn[tok * 64 + hf * 32];
#pragma unroll
    for (int j = 0; j < 4; j++) d4[j] = s4[j];
  }
  __syncthreads();
  u16* img = vkt + ((((size_t)b * 8 + kvh) * 8 + kt) << 13);   // 8192 u16 / image
#pragma unroll
  for (int i = 0; i < 4; i++) {
    int c = tid * 4 + i;                 // chunk index 0..1023
    int dd = c >> 4, chsw = c & 15;
    int ch = chsw ^ (dd & 15);
    u16 tmp[8];
#pragma unroll
    for (int p = 0; p < 8; p++) {
      int col = ch * 8 + p;
      int g = col >> 5, kl = col & 31;
      int kph = ((kl >> 2) & 1) * 16 + ((kl >> 4) & 1) * 8 + ((kl >> 3) & 1) * 4 + (kl & 3);
      tmp[p] = Vn[(g * 32 + kph) * 64 + dd];
    }
    *(uint4*)&img[c * 8] = *(const uint4*)tmp;
  }
}

// ---------------- flash attention v4 ----------------
// Grid (4, 32, 4) = 512 blocks = 2/CU. Two q-tiles per block (qtA=bx, qtB=7-bx):
// 9 tile-steps per block, K/V staged once for both. Transposed-score form,
// max-free exp2 softmax, P kept in registers via the k-permutation baked into
// the VkT images. K and VT double-buffered pure DMA. One barrier/iter.
// LDS: Ks 2x16KB + VT 2x16KB = 64KB -> 2 blocks/CU.
__global__ __launch_bounds__(256, 2) void flash_attn(const u16* __restrict__ qkv,
                                                     const u16* __restrict__ vkt,
                                                     u16* __restrict__ attn) {
  __shared__ u16 Ks[2][128 * 64];
  __shared__ u16 VT[2][64 * 128];

  const int tid = threadIdx.x;
  const int lane = tid & 63, wave = tid >> 6;
  const int quad = lane >> 4, l16 = lane & 15;
  const int qtA = blockIdx.x, qtB = 7 - blockIdx.x;
  const int h = blockIdx.y, b = blockIdx.z, kvh = h >> 2;
  const size_t tokBase = (size_t)b * 1024;
  const int qcol = h * 64, kcol = 2048 + kvh * 64;
  const int srow = tid >> 3, spc = tid & 7, ssc = spc ^ (srow & 7);

  auto stageK = [&](const u16* gbase, u16* L) {   // natural 128x64, swizzled chunks
#pragma unroll
    for (int i = 0; i < 4; i++)
      ld16_lds(gbase + (size_t)(srow + i * 32) * 3072 + ssc * 8, &L[tid * 8 + i * 2048]);
  };
  const u16* vimg = vkt + (((size_t)b * 8 + kvh) << 16);
  auto stageV = [&](int kt, u16* L) {             // pre-swizzled image: linear copy
    const u16* g = vimg + ((size_t)kt << 13);
#pragma unroll
    for (int i = 0; i < 4; i++)
      ld16_lds(g + i * 2048 + tid * 8, &L[tid * 8 + i * 2048]);
  };

  // ---- stage both Q tiles into the K buffers, extract fragments ----
  stageK(qkv + (tokBase + qtA * 128) * 3072 + qcol, Ks[0]);
  stageK(qkv + (tokBase + qtB * 128) * 3072 + qcol, Ks[1]);
  __syncthreads();
  bf16x8 qfA[2][2], qfB[2][2];   // B-frag: n=q=l16, kdim=d contiguous
#pragma unroll
  for (int nq = 0; nq < 2; nq++) {
    int qrow = wave * 32 + nq * 16 + l16;
#pragma unroll
    for (int ks = 0; ks < 2; ks++) {
      int c = (ks * 4 + quad) ^ (qrow & 7);
      qfA[nq][ks] = *(const bf16x8*)&Ks[0][qrow * 64 + c * 8];
      qfB[nq][ks] = *(const bf16x8*)&Ks[1][qrow * 64 + c * 8];
    }
  }
  __syncthreads();   // Q reads done before K DMA overwrites

  float lA[2] = {0.f, 0.f}, lB[2] = {0.f, 0.f};
  f32x4 oA[4][2] = {}, oB[4][2] = {};   // O^T: d=md*16+quad*4+r, q=nq*16+l16

  auto proc = [&](const bf16x8 (&kf)[2][2], const bf16x8 (&va)[4], const bf16x8 (&qf)[2][2],
                  f32x4 (&o)[4][2], float (&lacc)[2], bool msk, int c) {
    f32x4 s[2][2] = {};   // [nq][mkl]: k = (c*2+mkl)*16 + quad*4 + r, q = nq*16+l16
#pragma unroll
    for (int mkl = 0; mkl < 2; mkl++)
#pragma unroll
      for (int ks = 0; ks < 2; ks++) {
        s[0][mkl] = __builtin_amdgcn_mfma_f32_16x16x32_bf16(kf[mkl][ks], qf[0][ks], s[0][mkl], 0, 0, 0);
        s[1][mkl] = __builtin_amdgcn_mfma_f32_16x16x32_bf16(kf[mkl][ks], qf[1][ks], s[1][mkl], 0, 0, 0);
      }
    if (msk) {
#pragma unroll
      for (int nq = 0; nq < 2; nq++) {
        int q = wave * 32 + nq * 16 + l16;
#pragma unroll
        for (int mkl = 0; mkl < 2; mkl++)
#pragma unroll
          for (int r = 0; r < 4; r++)
            if ((c * 2 + mkl) * 16 + quad * 4 + r > q) s[nq][mkl][r] = -3e38f;
      }
    }
    bf16x8 pf[2];
#pragma unroll
    for (int nq = 0; nq < 2; nq++) {
      float a0 = 0.f;
#pragma unroll
      for (int mkl = 0; mkl < 2; mkl++)
#pragma unroll
        for (int r = 0; r < 4; r++) {
          float p = __builtin_amdgcn_exp2f(s[nq][mkl][r]);
          s[nq][mkl][r] = p;
          a0 += p;
        }
      lacc[nq] += a0;
      pf[nq][0] = (__bf16)s[nq][0][0]; pf[nq][1] = (__bf16)s[nq][0][1];
      pf[nq][2] = (__bf16)s[nq][0][2]; pf[nq][3] = (__bf16)s[nq][0][3];
      pf[nq][4] = (__bf16)s[nq][1][0]; pf[nq][5] = (__bf16)s[nq][1][1];
      pf[nq][6] = (__bf16)s[nq][1][2]; pf[nq][7] = (__bf16)s[nq][1][3];
    }
#pragma unroll
    for (int md = 0; md < 4; md++) {
      o[md][0] = __builtin_amdgcn_mfma_f32_16x16x32_bf16(va[md], pf[0], o[md][0], 0, 0, 0);
      o[md][1] = __builtin_amdgcn_mfma_f32_16x16x32_bf16(va[md], pf[1], o[md][1], 0, 0, 0);
    }
  };

  // ---- main loop: double-buffered K + VT DMA, one barrier per iteration ----
  stageK(qkv + tokBase * 3072 + kcol, Ks[0]);
  stageV(0, VT[0]);

  for (int kt = 0; kt <= qtB; kt++) {
    const int cur = kt & 1;
    __syncthreads();   // drains DMA for kt; all waves done with bufs[1-cur]
    if (kt < qtB) {
      stageK(qkv + (tokBase + (kt + 1) * 128) * 3072 + kcol, Ks[1 - cur]);
      stageV(kt + 1, VT[1 - cur]);
    }
    const bool doA = (kt <= qtA), mA = (kt == qtA), mB = (kt == qtB);
    const u16* K = Ks[cur];
    const u16* V = VT[cur];
#pragma unroll
    for (int c = 0; c < 4; c++) {
      bf16x8 kf[2][2];   // A-frag: m=krow=mk*16+l16, kdim=d
#pragma unroll
      for (int mkl = 0; mkl < 2; mkl++) {
        int krow = (c * 2 + mkl) * 16 + l16;
#pragma unroll
        for (int ks = 0; ks < 2; ks++)
          kf[mkl][ks] = *(const bf16x8*)&K[krow * 64 + ((ks * 4 + quad) ^ (krow & 7)) * 8];
      }
      bf16x8 va[4];      // A-frag V^T: m=d=md*16+l16, k-chunk c
#pragma unroll
      for (int md = 0; md < 4; md++) {
        int dd = md * 16 + l16;
        va[md] = *(const bf16x8*)&V[dd * 128 + ((c * 4 + quad) ^ l16) * 8];
      }
      proc(kf, va, qfB, oB, lB, mB, c);
      if (doA) proc(kf, va, qfA, oA, lA, mA, c);
    }
  }

  // ---- epilogue: reduce l across quads (2 shfls), O/l, b64 stores ----
  auto epilogue = [&](const f32x4 (&o)[4][2], const float (&lacc)[2], int qt_tile) {
#pragma unroll
    for (int nq = 0; nq < 2; nq++) {
      float l = lacc[nq];
      l += __shfl_xor(l, 16);
      l += __shfl_xor(l, 32);
      float inv = 1.0f / l;
      int t = qt_tile * 128 + wave * 32 + nq * 16 + l16;
      size_t rowOff = (tokBase + t) * 2048 + qcol;
#pragma unroll
      for (int md = 0; md < 4; md++) {
        bf16x4 w;
        w[0] = (__bf16)(o[md][nq][0] * inv);
        w[1] = (__bf16)(o[md][nq][1] * inv);
        w[2] = (__bf16)(o[md][nq][2] * inv);
        w[3] = (__bf16)(o[md][nq][3] * inv);
        *(bf16x4*)&attn[rowOff + md * 16 + quad * 4] = w;
      }
    }
  };
  epilogue(oB, lB, qtB);
  epilogue(oA, lA, qtA);
}

// ---------------- launch ----------------
extern "C" void kernel_launch(void* const* d_in, const int* in_sizes, int n_in,
                              void* d_out, int out_size, void* d_ws, size_t ws_size,
                              hipStream_t stream) {
  const float* hs = (const float*)d_in[0];
  const float* cs = (const float*)d_in[1];
  const float* sn = (const float*)d_in[2];
  const float* Wq = (const float*)d_in[3];
  const float* Wk = (const float*)d_in[4];
  const float* Wv = (const float*)d_in[5];
  const float* Wo = (const float*)d_in[6];
  float* out = (float*)d_out;

  char* ws = (char*)d_ws;
  u16* hsB   = (u16*)(ws);                  // 4096x2048 bf16 (dead after qkv GEMM)
  u16* vkt   = (u16*)(ws);                  // 4MB VkT images, built after qkv GEMM
  u16* wqkvT = (u16*)(ws + 16777216);       // 3072x2048 bf16 [WqT;WkT;WvT]
  u16* woT   = (u16*)(ws + 29360128);       // 2048x2048 bf16
  u16* qkv   = (u16*)(ws + 37748736);       // 4096x3072 bf16
  u16* attnB = (u16*)(ws + 62914560);       // 4096x2048 bf16

  // attention scale folded into Wq: 1/8 * log2(e)
  const float QSCALE = 0.18033688011112042f;

  prep<<<18432, 256, 0, stream>>>(hs, hsB, Wq, Wk, Wv, Wo, wqkvT, woT, QSCALE);
  gemm_bt<u16, true><<<dim3(24, 32), 256, 0, stream>>>(hsB, wqkvT, qkv, 4096, 3072, 2048, cs, sn);
  vkt_build<<<dim3(8, 8, 4), 256, 0, stream>>>(qkv, vkt);
  flash_attn<<<dim3(4, 32, 4), 256, 0, stream>>>(qkv, vkt, attnB);
  gemm_bt<float, false><<<dim3(16, 32), 256, 0, stream>>>(attnB, woT, out, 4096, 2048, 2048,
                                                          nullptr, nullptr);
}

// Round 7
// 309.884 us; speedup vs baseline: 1.0044x; 1.0044x over previous
//
#include <hip/hip_runtime.h>
#include <type_traits>

// Problem constants (ExaoneFlashAttention): B=4, S=1024, T=4096, D_MODEL=2048,
// H=32, KVH=8, HD=64, GROUPS=4, SCALE=1/8. All bf16 MFMA, f32 accum.
// Attention scale * log2(e) folded into Wq transpose -> softmax in exp2 domain.
// Max-free softmax (logits bounded); RoPE fused into the QKV GEMM epilogue.
// GEMM staging: R4 config (BK=32, simple XOR swizzle, 16KB LDS) — measured
// fastest (75.7us QKV) vs BK=64 (88us, R5) and paired-row BK=32 (113us, R6).

typedef __bf16 bf16x8 __attribute__((ext_vector_type(8)));
typedef __bf16 bf16x4 __attribute__((ext_vector_type(4)));
typedef float f32x4 __attribute__((ext_vector_type(4)));
typedef unsigned short u16;
typedef unsigned int u32;

#define DEVI __device__ __forceinline__

DEVI u16 f2bf(float f) {           // RNE f32->bf16 (finite inputs)
  u32 u = __builtin_bit_cast(u32, f);
  u += 0x7FFF + ((u >> 16) & 1);
  return (u16)(u >> 16);
}

// async global->LDS, 16B per lane. LDS dest must be wave-uniform base + lane*16.
DEVI void ld16_lds(const void* g, void* l) {
  __builtin_amdgcn_global_load_lds((const __attribute__((address_space(1))) u32*)g,
                                   (__attribute__((address_space(3))) u32*)l, 16, 0, 0);
}

// ---------------- merged prep: hs f32->bf16 convert + 4 weight transposes ----------------
// blockIdx.x ranges: [0,8192) convert; then Wq 64x64, Wk 16x64, Wv 16x64, Wo 64x64.
__global__ __launch_bounds__(256) void prep(const float* __restrict__ hs, u16* __restrict__ hsB,
                                            const float* __restrict__ Wq, const float* __restrict__ Wk,
                                            const float* __restrict__ Wv, const float* __restrict__ Wo,
                                            u16* __restrict__ wqkvT, u16* __restrict__ woT,
                                            float qscale) {
  int bx = blockIdx.x;
  if (bx < 8192) {                     // convert: 8192*256*4 = 4096*2048 elements
    int i = bx * 256 + threadIdx.x;
    float4 v = ((const float4*)hs)[i];
    ushort4 o;
    o.x = f2bf(v.x); o.y = f2bf(v.y); o.z = f2bf(v.z); o.w = f2bf(v.w);
    ((ushort4*)hsB)[i] = o;
    return;
  }
  bx -= 8192;
  const float* src; u16* dst; int C; float scale; int bxx, bxy;
  if (bx < 4096)      { src = Wq; dst = wqkvT;                      C = 2048; scale = qscale;
                        bxx = bx & 63; bxy = bx >> 6; }
  else if (bx < 5120) { bx -= 4096; src = Wk; dst = wqkvT + (size_t)2048 * 2048; C = 512; scale = 1.f;
                        bxx = bx & 15; bxy = bx >> 4; }
  else if (bx < 6144) { bx -= 5120; src = Wv; dst = wqkvT + (size_t)2560 * 2048; C = 512; scale = 1.f;
                        bxx = bx & 15; bxy = bx >> 4; }
  else                { bx -= 6144; src = Wo; dst = woT;            C = 2048; scale = 1.f;
                        bxx = bx & 63; bxy = bx >> 6; }
  const int R = 2048;
  __shared__ float tile[32][33];
  int c0 = bxx * 32, r0 = bxy * 32;
  int tx = threadIdx.x & 31, ty = threadIdx.x >> 5;   // ty 0..7
#pragma unroll
  for (int i = 0; i < 32; i += 8)
    tile[ty + i][tx] = src[(size_t)(r0 + ty + i) * C + (c0 + tx)];
  __syncthreads();
#pragma unroll
  for (int i = 0; i < 32; i += 8)
    dst[(size_t)(c0 + ty + i) * R + (r0 + tx)] = f2bf(tile[tx][ty + i] * scale);
}

// ---------------- GEMM: C(MxN) = A(MxK) * BT(NxK)^T, bf16 in, f32 acc ----------------
// 128x128 tile, 256 thr (4 waves, each 64x64 = 4x4 MFMA tiles), BK=32.
// R4 staging: srow=tid>>2, chunk=(tid&3)^(srow&3), 16KB LDS total.
// ROPE: rotary applied in-register before the bf16 pack (QKV gemm, cols < 2560;
// pair (d, d+32) = (acc[i][j], acc[i][j+2]) of the same lane).
template <typename OutT, bool ROPE>
__global__ __launch_bounds__(256) void gemm_bt(const u16* __restrict__ A, const u16* __restrict__ BT,
                                               OutT* __restrict__ C, int M, int N, int K,
                                               const float* __restrict__ cs,
                                               const float* __restrict__ sn) {
  __shared__ u16 As[128 * 32];
  __shared__ u16 Bs[128 * 32];
  const int tid = threadIdx.x;
  const int lane = tid & 63, wave = tid >> 6;
  const int quad = lane >> 4, l16 = lane & 15;
  const int m0 = blockIdx.y * 128, n0 = blockIdx.x * 128;
  const int wr = (wave >> 1) * 64, wc = (wave & 1) * 64;

  f32x4 acc[4][4] = {};

  const int srow = tid >> 2;                    // 0..63
  const int sc = (tid & 3) ^ (srow & 3);        // swizzled source chunk (16B units)
  const u16* Ag0 = A + (size_t)(m0 + srow) * K + sc * 8;
  const u16* Ag1 = A + (size_t)(m0 + srow + 64) * K + sc * 8;
  const u16* Bg0 = BT + (size_t)(n0 + srow) * K + sc * 8;
  const u16* Bg1 = BT + (size_t)(n0 + srow + 64) * K + sc * 8;
  u16* Ad0 = &As[tid * 8];
  u16* Ad1 = &As[tid * 8 + 64 * 32];
  u16* Bd0 = &Bs[tid * 8];
  u16* Bd1 = &Bs[tid * 8 + 64 * 32];

  for (int k0 = 0; k0 < K; k0 += 32) {
    __syncthreads();
    ld16_lds(Ag0 + k0, Ad0);
    ld16_lds(Ag1 + k0, Ad1);
    ld16_lds(Bg0 + k0, Bd0);
    ld16_lds(Bg1 + k0, Bd1);
    __syncthreads();   // vmcnt drain before use

    bf16x8 af[4], bfr[4];
#pragma unroll
    for (int i = 0; i < 4; i++) {
      int ar = wr + i * 16 + l16;
      af[i] = *(const bf16x8*)&As[ar * 32 + (quad ^ (ar & 3)) * 8];
      int br = wc + i * 16 + l16;
      bfr[i] = *(const bf16x8*)&Bs[br * 32 + (quad ^ (br & 3)) * 8];
    }
#pragma unroll
    for (int i = 0; i < 4; i++)
#pragma unroll
      for (int j = 0; j < 4; j++)
        acc[i][j] = __builtin_amdgcn_mfma_f32_16x16x32_bf16(af[i], bfr[j], acc[i][j], 0, 0, 0);
  }

  // ---- fused RoPE (QKV gemm, Q/K columns only; wave-uniform branch) ----
  if constexpr (ROPE) {
    if (n0 + wc < 2560) {
#pragma unroll
      for (int i = 0; i < 4; i++) {
        int t0 = m0 + wr + i * 16 + quad * 4;
#pragma unroll
        for (int jj = 0; jj < 2; jj++) {
          int d = jj * 16 + l16;            // head-dim 0..31
#pragma unroll
          for (int r = 0; r < 4; r++) {
            float c = cs[(size_t)(t0 + r) * 32 + d];
            float s = sn[(size_t)(t0 + r) * 32 + d];
            float x1 = acc[i][jj][r], x2 = acc[i][jj + 2][r];
            acc[i][jj][r] = x1 * c - x2 * s;
            acc[i][jj + 2][r] = x2 * c + x1 * s;
          }
        }
      }
    }
  }

  // epilogue: C/D layout col=lane&15, row=quad*4+r
#pragma unroll
  for (int i = 0; i < 4; i++) {
    int row = m0 + wr + i * 16 + quad * 4;
#pragma unroll
    for (int j = 0; j < 4; j++) {
      int col = n0 + wc + j * 16 + l16;
#pragma unroll
      for (int r = 0; r < 4; r++) {
        size_t off = (size_t)(row + r) * N + col;
        if constexpr (sizeof(OutT) == 2) C[off] = f2bf(acc[i][j][r]);
        else C[off] = acc[i][j][r];
      }
    }
  }
}

// ---------------- vkt_build: V -> transposed, chunk-swizzled, k-permuted tile images ----
__global__ __launch_bounds__(256) void vkt_build(const u16* __restrict__ qkv,
                                                 u16* __restrict__ vkt) {
  __shared__ u16 Vn[128 * 64];
  const int kt = blockIdx.x, kvh = blockIdx.y, b = blockIdx.z;
  const int tid = threadIdx.x;
  const u16* src = qkv + ((size_t)b * 1024 + kt * 128) * 3072 + 2560 + kvh * 64;
  {
    int tok = tid >> 1, hf = tid & 1;
    const uint4* s4 = (const uint4*)(src + (size_t)tok * 3072 + hf * 32);
    uint4* d4 = (uint4*)&Vn[tok * 64 + hf * 32];
#pragma unroll
    for (int j = 0; j < 4; j++) d4[j] = s4[j];
  }
  __syncthreads();
  u16* img = vkt + ((((size_t)b * 8 + kvh) * 8 + kt) << 13);   // 8192 u16 / image
#pragma unroll
  for (int i = 0; i < 4; i++) {
    int c = tid * 4 + i;                 // chunk index 0..1023
    int dd = c >> 4, chsw = c & 15;
    int ch = chsw ^ (dd & 15);
    u16 tmp[8];
#pragma unroll
    for (int p = 0; p < 8; p++) {
      int col = ch * 8 + p;
      int g = col >> 5, kl = col & 31;
      int kph = ((kl >> 2) & 1) * 16 + ((kl >> 4) & 1) * 8 + ((kl >> 3) & 1) * 4 + (kl & 3);
      tmp[p] = Vn[(g * 32 + kph) * 64 + dd];
    }
    *(uint4*)&img[c * 8] = *(const uint4*)tmp;
  }
}

// ---------------- flash attention v4 ----------------
// Grid (4, 32, 4) = 512 blocks = 2/CU. Two q-tiles per block (qtA=bx, qtB=7-bx):
// 9 tile-steps per block, K/V staged once for both. Transposed-score form,
// max-free exp2 softmax, P kept in registers via the k-permutation baked into
// the VkT images. K and VT double-buffered pure DMA. One barrier/iter.
// LDS: Ks 2x16KB + VT 2x16KB = 64KB -> 2 blocks/CU.
__global__ __launch_bounds__(256, 2) void flash_attn(const u16* __restrict__ qkv,
                                                     const u16* __restrict__ vkt,
                                                     u16* __restrict__ attn) {
  __shared__ u16 Ks[2][128 * 64];
  __shared__ u16 VT[2][64 * 128];

  const int tid = threadIdx.x;
  const int lane = tid & 63, wave = tid >> 6;
  const int quad = lane >> 4, l16 = lane & 15;
  const int qtA = blockIdx.x, qtB = 7 - blockIdx.x;
  const int h = blockIdx.y, b = blockIdx.z, kvh = h >> 2;
  const size_t tokBase = (size_t)b * 1024;
  const int qcol = h * 64, kcol = 2048 + kvh * 64;
  const int srow = tid >> 3, spc = tid & 7, ssc = spc ^ (srow & 7);

  auto stageK = [&](const u16* gbase, u16* L) {   // natural 128x64, swizzled chunks
#pragma unroll
    for (int i = 0; i < 4; i++)
      ld16_lds(gbase + (size_t)(srow + i * 32) * 3072 + ssc * 8, &L[tid * 8 + i * 2048]);
  };
  const u16* vimg = vkt + (((size_t)b * 8 + kvh) << 16);
  auto stageV = [&](int kt, u16* L) {             // pre-swizzled image: linear copy
    const u16* g = vimg + ((size_t)kt << 13);
#pragma unroll
    for (int i = 0; i < 4; i++)
      ld16_lds(g + i * 2048 + tid * 8, &L[tid * 8 + i * 2048]);
  };

  // ---- stage both Q tiles into the K buffers, extract fragments ----
  stageK(qkv + (tokBase + qtA * 128) * 3072 + qcol, Ks[0]);
  stageK(qkv + (tokBase + qtB * 128) * 3072 + qcol, Ks[1]);
  __syncthreads();
  bf16x8 qfA[2][2], qfB[2][2];   // B-frag: n=q=l16, kdim=d contiguous
#pragma unroll
  for (int nq = 0; nq < 2; nq++) {
    int qrow = wave * 32 + nq * 16 + l16;
#pragma unroll
    for (int ks = 0; ks < 2; ks++) {
      int c = (ks * 4 + quad) ^ (qrow & 7);
      qfA[nq][ks] = *(const bf16x8*)&Ks[0][qrow * 64 + c * 8];
      qfB[nq][ks] = *(const bf16x8*)&Ks[1][qrow * 64 + c * 8];
    }
  }
  __syncthreads();   // Q reads done before K DMA overwrites

  float lA[2] = {0.f, 0.f}, lB[2] = {0.f, 0.f};
  f32x4 oA[4][2] = {}, oB[4][2] = {};   // O^T: d=md*16+quad*4+r, q=nq*16+l16

  auto proc = [&](const bf16x8 (&kf)[2][2], const bf16x8 (&va)[4], const bf16x8 (&qf)[2][2],
                  f32x4 (&o)[4][2], float (&lacc)[2], bool msk, int c) {
    f32x4 s[2][2] = {};   // [nq][mkl]: k = (c*2+mkl)*16 + quad*4 + r, q = nq*16+l16
#pragma unroll
    for (int mkl = 0; mkl < 2; mkl++)
#pragma unroll
      for (int ks = 0; ks < 2; ks++) {
        s[0][mkl] = __builtin_amdgcn_mfma_f32_16x16x32_bf16(kf[mkl][ks], qf[0][ks], s[0][mkl], 0, 0, 0);
        s[1][mkl] = __builtin_amdgcn_mfma_f32_16x16x32_bf16(kf[mkl][ks], qf[1][ks], s[1][mkl], 0, 0, 0);
      }
    if (msk) {
#pragma unroll
      for (int nq = 0; nq < 2; nq++) {
        int q = wave * 32 + nq * 16 + l16;
#pragma unroll
        for (int mkl = 0; mkl < 2; mkl++)
#pragma unroll
          for (int r = 0; r < 4; r++)
            if ((c * 2 + mkl) * 16 + quad * 4 + r > q) s[nq][mkl][r] = -3e38f;
      }
    }
    bf16x8 pf[2];
#pragma unroll
    for (int nq = 0; nq < 2; nq++) {
      float a0 = 0.f;
#pragma unroll
      for (int mkl = 0; mkl < 2; mkl++)
#pragma unroll
        for (int r = 0; r < 4; r++) {
          float p = __builtin_amdgcn_exp2f(s[nq][mkl][r]);
          s[nq][mkl][r] = p;
          a0 += p;
        }
      lacc[nq] += a0;
      pf[nq][0] = (__bf16)s[nq][0][0]; pf[nq][1] = (__bf16)s[nq][0][1];
      pf[nq][2] = (__bf16)s[nq][0][2]; pf[nq][3] = (__bf16)s[nq][0][3];
      pf[nq][4] = (__bf16)s[nq][1][0]; pf[nq][5] = (__bf16)s[nq][1][1];
      pf[nq][6] = (__bf16)s[nq][1][2]; pf[nq][7] = (__bf16)s[nq][1][3];
    }
#pragma unroll
    for (int md = 0; md < 4; md++) {
      o[md][0] = __builtin_amdgcn_mfma_f32_16x16x32_bf16(va[md], pf[0], o[md][0], 0, 0, 0);
      o[md][1] = __builtin_amdgcn_mfma_f32_16x16x32_bf16(va[md], pf[1], o[md][1], 0, 0, 0);
    }
  };

  // ---- main loop: double-buffered K + VT DMA, one barrier per iteration ----
  stageK(qkv + tokBase * 3072 + kcol, Ks[0]);
  stageV(0, VT[0]);

  for (int kt = 0; kt <= qtB; kt++) {
    const int cur = kt & 1;
    __syncthreads();   // drains DMA for kt; all waves done with bufs[1-cur]
    if (kt < qtB) {
      stageK(qkv + (tokBase + (kt + 1) * 128) * 3072 + kcol, Ks[1 - cur]);
      stageV(kt + 1, VT[1 - cur]);
    }
    const bool doA = (kt <= qtA), mA = (kt == qtA), mB = (kt == qtB);
    const u16* K = Ks[cur];
    const u16* V = VT[cur];
#pragma unroll
    for (int c = 0; c < 4; c++) {
      bf16x8 kf[2][2];   // A-frag: m=krow=mk*16+l16, kdim=d
#pragma unroll
      for (int mkl = 0; mkl < 2; mkl++) {
        int krow = (c * 2 + mkl) * 16 + l16;
#pragma unroll
        for (int ks = 0; ks < 2; ks++)
          kf[mkl][ks] = *(const bf16x8*)&K[krow * 64 + ((ks * 4 + quad) ^ (krow & 7)) * 8];
      }
      bf16x8 va[4];      // A-frag V^T: m=d=md*16+l16, k-chunk c
#pragma unroll
      for (int md = 0; md < 4; md++) {
        int dd = md * 16 + l16;
        va[md] = *(const bf16x8*)&V[dd * 128 + ((c * 4 + quad) ^ l16) * 8];
      }
      proc(kf, va, qfB, oB, lB, mB, c);
      if (doA) proc(kf, va, qfA, oA, lA, mA, c);
    }
  }

  // ---- epilogue: reduce l across quads (2 shfls), O/l, b64 stores ----
  auto epilogue = [&](const f32x4 (&o)[4][2], const float (&lacc)[2], int qt_tile) {
#pragma unroll
    for (int nq = 0; nq < 2; nq++) {
      float l = lacc[nq];
      l += __shfl_xor(l, 16);
      l += __shfl_xor(l, 32);
      float inv = 1.0f / l;
      int t = qt_tile * 128 + wave * 32 + nq * 16 + l16;
      size_t rowOff = (tokBase + t) * 2048 + qcol;
#pragma unroll
      for (int md = 0; md < 4; md++) {
        bf16x4 w;
        w[0] = (__bf16)(o[md][nq][0] * inv);
        w[1] = (__bf16)(o[md][nq][1] * inv);
        w[2] = (__bf16)(o[md][nq][2] * inv);
        w[3] = (__bf16)(o[md][nq][3] * inv);
        *(bf16x4*)&attn[rowOff + md * 16 + quad * 4] = w;
      }
    }
  };
  epilogue(oB, lB, qtB);
  epilogue(oA, lA, qtA);
}

// ---------------- launch ----------------
extern "C" void kernel_launch(void* const* d_in, const int* in_sizes, int n_in,
                              void* d_out, int out_size, void* d_ws, size_t ws_size,
                              hipStream_t stream) {
  const float* hs = (const float*)d_in[0];
  const float* cs = (const float*)d_in[1];
  const float* sn = (const float*)d_in[2];
  const float* Wq = (const float*)d_in[3];
  const float* Wk = (const float*)d_in[4];
  const float* Wv = (const float*)d_in[5];
  const float* Wo = (const float*)d_in[6];
  float* out = (float*)d_out;

  char* ws = (char*)d_ws;
  u16* hsB   = (u16*)(ws);                  // 4096x2048 bf16 (dead after qkv GEMM)
  u16* vkt   = (u16*)(ws);                  // 4MB VkT images, built after qkv GEMM
  u16* wqkvT = (u16*)(ws + 16777216);       // 3072x2048 bf16 [WqT;WkT;WvT]
  u16* woT   = (u16*)(ws + 29360128);       // 2048x2048 bf16
  u16* qkv   = (u16*)(ws + 37748736);       // 4096x3072 bf16
  u16* attnB = (u16*)(ws + 62914560);       // 4096x2048 bf16

  // attention scale folded into Wq: 1/8 * log2(e)
  const float QSCALE = 0.18033688011112042f;

  prep<<<18432, 256, 0, stream>>>(hs, hsB, Wq, Wk, Wv, Wo, wqkvT, woT, QSCALE);
  gemm_bt<u16, true><<<dim3(24, 32), 256, 0, stream>>>(hsB, wqkvT, qkv, 4096, 3072, 2048, cs, sn);
  vkt_build<<<dim3(8, 8, 4), 256, 0, stream>>>(qkv, vkt);
  flash_attn<<<dim3(4, 32, 4), 256, 0, stream>>>(qkv, vkt, attnB);
  gemm_bt<float, false><<<dim3(16, 32), 256, 0, stream>>>(attnB, woT, out, 4096, 2048, 2048,
                                                          nullptr, nullptr);
}